// Round 10
// baseline (228.512 us; speedup 1.0000x reference)
//
#include <hip/hip_runtime.h>
#include <cmath>

#define B_ 2
#define H_ 8
#define S_ 2048
#define D_ 64
#define TS 64          // Q rows per block
#define KV 128         // K/V rows per tile
#define NTT (S_ / KV)  // 16
#define LDST 68

typedef __attribute__((ext_vector_type(8))) _Float16 f16x8;
typedef __attribute__((ext_vector_type(4))) float f32x4;

// ---------------------------------------------------------------------------
// prep pass 1: Ap = (relu(W@A + b) + eps)^pw      grid (B*H, 4), 16 f-rows/blk
// ---------------------------------------------------------------------------
__global__ __launch_bounds__(256) void prep_Ap(
    const float* __restrict__ A, const float* __restrict__ W,
    const float* __restrict__ bb, const float* __restrict__ pw,
    float* __restrict__ Ap)
{
    __shared__ float sA[64 * LDST];
    __shared__ float sW[16 * LDST];
    const int tid = threadIdx.x;
    const int bh = blockIdx.x, h = bh & 7, fs = blockIdx.y << 4;

    const float4* A4 = (const float4*)(A + bh * 4096);
#pragma unroll
    for (int it = 0; it < 4; ++it) {
        int idx = tid + it * 256;
        int r = idx >> 4, c = idx & 15;
        *(float4*)&sA[r * LDST + c * 4] = A4[idx];
    }
    {
        int r = tid >> 4, c = tid & 15;
        *(float4*)&sW[r * LDST + c * 4] =
            *(const float4*)(W + (h * 64 + fs + r) * 64 + c * 4);
    }
    __syncthreads();

    const int ty = tid >> 4, tx = tid & 15;
    float a0 = 0, a1 = 0, a2 = 0, a3 = 0;
    for (int d = 0; d < 64; ++d) {
        float4 a4 = *(const float4*)&sA[d * LDST + tx * 4];
        float w = sW[ty * LDST + d];
        a0 += w * a4.x; a1 += w * a4.y; a2 += w * a4.z; a3 += w * a4.w;
    }
    int f = fs + ty;
    float4 b4 = *(const float4*)&bb[(h * 64 + f) * 64 + tx * 4];
    float4 p4 = *(const float4*)&pw[(h * 64 + f) * 64 + tx * 4];
    float4 o;
    o.x = exp2f(p4.x * __log2f(fmaxf(a0 + b4.x, 0.f) + 1e-9f));
    o.y = exp2f(p4.y * __log2f(fmaxf(a1 + b4.y, 0.f) + 1e-9f));
    o.z = exp2f(p4.z * __log2f(fmaxf(a2 + b4.z, 0.f) + 1e-9f));
    o.w = exp2f(p4.w * __log2f(fmaxf(a3 + b4.w, 0.f) + 1e-9f));
    *(float4*)&Ap[(bh * 64 + f) * 64 + tx * 4] = o;
}

// ---------------------------------------------------------------------------
// prep pass 2: avAp = a_vec @ Ap + ba             grid (B*H, 4)
// ---------------------------------------------------------------------------
__global__ __launch_bounds__(256) void prep_avAp2(
    const float* __restrict__ Ap, const float* __restrict__ av,
    const float* __restrict__ ba, float* __restrict__ avAp)
{
    __shared__ float sA[64 * LDST];
    __shared__ float sW[16 * LDST];
    const int tid = threadIdx.x;
    const int bh = blockIdx.x, h = bh & 7, fs = blockIdx.y << 4;

    const float4* A4 = (const float4*)(Ap + bh * 4096);
#pragma unroll
    for (int it = 0; it < 4; ++it) {
        int idx = tid + it * 256;
        int r = idx >> 4, c = idx & 15;
        *(float4*)&sA[r * LDST + c * 4] = A4[idx];
    }
    {
        int r = tid >> 4, c = tid & 15;
        *(float4*)&sW[r * LDST + c * 4] =
            *(const float4*)(av + (h * 64 + fs + r) * 64 + c * 4);
    }
    __syncthreads();

    const int ty = tid >> 4, tx = tid & 15;
    float a0 = 0, a1 = 0, a2 = 0, a3 = 0;
    for (int d = 0; d < 64; ++d) {
        float4 a4 = *(const float4*)&sA[d * LDST + tx * 4];
        float w = sW[ty * LDST + d];
        a0 += w * a4.x; a1 += w * a4.y; a2 += w * a4.z; a3 += w * a4.w;
    }
    int f = fs + ty;
    float4 b4 = *(const float4*)&ba[(h * 64 + f) * 64 + tx * 4];
    *(float4*)&avAp[(bh * 64 + f) * 64 + tx * 4] =
        make_float4(a0 + b4.x, a1 + b4.y, a2 + b4.z, a3 + b4.w);
}

// ---------------------------------------------------------------------------
// flash5: flash4's proven 3-barrier single-buffer skeleton, KV tile = 128.
// LDS map (73728 B):
//   KH@0(16K) KL@16384(16K) VT@32768(16K) P@49152(4x4K) MROW@65536(8K)
// Prologue overlays (all before K staging, protected by extra barrier):
//   AVP@0(17408) HIN@17408(17408) QP@34816(17408)
// Barriers/tile: [1] P visible  [2] tile reads drained  [3] staging visible
// ---------------------------------------------------------------------------
#define KH_S 0
#define KL_S 16384
#define VT_S 32768
#define P_S  49152
#define MROW_S 65536
#define QP_S 34816
#define AVP_S 0
#define HIN_S 17408
#define SMEM_SZ 73728

__global__ __launch_bounds__(256) void flash5(
    const float* __restrict__ Hin, const float* __restrict__ Hk,
    const float* __restrict__ Hv, const float* __restrict__ maskg,
    const float* __restrict__ avAp, float* __restrict__ out)
{
    __shared__ __align__(16) char smem[SMEM_SZ];
    float* AVP = (float*)(smem + AVP_S);
    float* HIN = (float*)(smem + HIN_S);
    float* QP  = (float*)(smem + QP_S);
    float* MROW = (float*)(smem + MROW_S);

    const int tid = threadIdx.x;
    const int wave = tid >> 6, lane = tid & 63;
    const int l15 = lane & 15, lg = lane >> 4;
    const int qt = blockIdx.x, bh = blockIdx.y;
    const int b = bh >> 3;
    const size_t base = (size_t)bh * S_ * D_;
    const int q0 = qt * TS;

    // ---- Phase A: Qp = Hin_tile @ avAp (f32 in LDS) ----
    {
        const float4* a4 = (const float4*)(avAp + bh * D_ * D_);
        const float4* h4 = (const float4*)(Hin + base + (size_t)q0 * D_);
#pragma unroll
        for (int i = 0; i < 4; ++i) {
            int f = tid + i * 256;
            int r = f >> 4, c = (f & 15) * 4;
            *(float4*)&AVP[r * LDST + c] = a4[f];
            *(float4*)&HIN[r * LDST + c] = h4[f];
        }
    }
    __syncthreads();
    {
        const int tx = tid & 15, ty = tid >> 4;
        float acc[4][4] = {};
        for (int d = 0; d < D_; ++d) {
            float4 av = *(const float4*)&AVP[d * LDST + tx * 4];
#pragma unroll
            for (int rr = 0; rr < 4; ++rr) {
                float h = HIN[(ty * 4 + rr) * LDST + d];
                acc[rr][0] += h * av.x; acc[rr][1] += h * av.y;
                acc[rr][2] += h * av.z; acc[rr][3] += h * av.w;
            }
        }
#pragma unroll
        for (int rr = 0; rr < 4; ++rr)
            *(float4*)&QP[(ty * 4 + rr) * LDST + tx * 4] =
                make_float4(acc[rr][0], acc[rr][1], acc[rr][2], acc[rr][3]);
    }
    __syncthreads();

    // ---- extract Q A-frags (x0.125 folded), hi/lo f16 ----
    f16x8 qAh[2], qAl[2];
#pragma unroll
    for (int kc = 0; kc < 2; ++kc) {
        int row = wave * 16 + l15;
        int k0 = kc * 32 + lg * 8;
        float4 v0 = *(const float4*)&QP[row * LDST + k0];
        float4 v1 = *(const float4*)&QP[row * LDST + k0 + 4];
        float xs[8] = {v0.x, v0.y, v0.z, v0.w, v1.x, v1.y, v1.z, v1.w};
#pragma unroll
        for (int j = 0; j < 8; ++j) {
            float x = xs[j] * 0.125f;
            _Float16 hh = (_Float16)x;
            qAh[kc][j] = hh;
            qAl[kc][j] = (_Float16)(x - (float)hh);
        }
    }
    __syncthreads();   // QP overlaps VT/P: all QP reads done before staging

    // ---- stage helpers (single buffer, KV=128) ----
    float4 kreg[4][2], vreg[4][2];
    auto stage_load_K = [&](int kt) {
        const float* Kg = Hk + base + (size_t)kt * KV * D_;
#pragma unroll
        for (int i = 0; i < 4; ++i) {
            int c = tid + i * 256;
            kreg[i][0] = *(const float4*)(Kg + c * 8);
            kreg[i][1] = *(const float4*)(Kg + c * 8 + 4);
        }
    };
    auto stage_load_V = [&](int kt) {
        const float* Vg = Hv + base + (size_t)kt * KV * D_;
#pragma unroll
        for (int i = 0; i < 4; ++i) {
            int c = tid + i * 256;
            vreg[i][0] = *(const float4*)(Vg + c * 8);
            vreg[i][1] = *(const float4*)(Vg + c * 8 + 4);
        }
    };
    auto stage_write = [&]() {
#pragma unroll
        for (int i = 0; i < 4; ++i) {
            int c = tid + i * 256;
            int r = c >> 3, c8 = c & 7;
            float xs[8] = {kreg[i][0].x, kreg[i][0].y, kreg[i][0].z, kreg[i][0].w,
                           kreg[i][1].x, kreg[i][1].y, kreg[i][1].z, kreg[i][1].w};
            f16x8 h, l;
#pragma unroll
            for (int e = 0; e < 8; ++e) {
                _Float16 hh = (_Float16)xs[e];
                h[e] = hh; l[e] = (_Float16)(xs[e] - (float)hh);
            }
            int byte = (r * 128 + c8 * 16) ^ ((r & 7) << 4);
            *(f16x8*)(smem + KH_S + byte) = h;
            *(f16x8*)(smem + KL_S + byte) = l;
            float vs[8] = {vreg[i][0].x, vreg[i][0].y, vreg[i][0].z, vreg[i][0].w,
                           vreg[i][1].x, vreg[i][1].y, vreg[i][1].z, vreg[i][1].w};
#pragma unroll
            for (int e = 0; e < 8; ++e) {
                int vr = c8 * 8 + e;                        // d
                int vb = (vr * 256 + r * 2) ^
                         ((((vr & 7) ^ ((vr >> 3) & 7)) << 4));
                *(_Float16*)(smem + VT_S + vb) = (_Float16)vs[e];
            }
        }
    };

    // ---- prologue: tile 0 staged + mask row ----
    stage_load_K(0);
    stage_load_V(0);
    stage_write();
    for (int i = tid; i < S_; i += 256) MROW[i] = -1e9f * maskg[b * S_ + i];
    __syncthreads();

    float mrun[4], lrun[4];
    f32x4 o[4];
#pragma unroll
    for (int i = 0; i < 4; ++i) {
        mrun[i] = -INFINITY; lrun[i] = 0.f;
        o[i] = (f32x4){0.f, 0.f, 0.f, 0.f};
    }

    for (int kt = 0; kt < NTT; ++kt) {
        if (kt + 1 < NTT) stage_load_K(kt + 1);

        // -- QK^T: S(16x128) = Q @ K^T, 3-term hi/lo --
        f32x4 s[8];
#pragma unroll
        for (int ns = 0; ns < 8; ++ns) s[ns] = (f32x4){0.f, 0.f, 0.f, 0.f};
        __builtin_amdgcn_s_setprio(1);
#pragma unroll
        for (int ns = 0; ns < 8; ++ns)
#pragma unroll
            for (int kc = 0; kc < 2; ++kc) {
                int row = ns * 16 + l15;
                int byte = (row * 128 + kc * 64 + lg * 16) ^ ((row & 7) << 4);
                f16x8 kh = *(const f16x8*)(smem + KH_S + byte);
                f16x8 kl = *(const f16x8*)(smem + KL_S + byte);
                s[ns] = __builtin_amdgcn_mfma_f32_16x16x32_f16(qAh[kc], kh, s[ns], 0, 0, 0);
                s[ns] = __builtin_amdgcn_mfma_f32_16x16x32_f16(qAl[kc], kh, s[ns], 0, 0, 0);
                s[ns] = __builtin_amdgcn_mfma_f32_16x16x32_f16(qAh[kc], kl, s[ns], 0, 0, 0);
            }
        __builtin_amdgcn_s_setprio(0);

        if (kt + 1 < NTT) stage_load_V(kt + 1);

        // -- leaky + mask + online softmax (row = lg*4+r, col = ns*16+l15) --
        float mk[8];
#pragma unroll
        for (int ns = 0; ns < 8; ++ns) mk[ns] = MROW[kt * KV + ns * 16 + l15];
        float scs[4];
#pragma unroll
        for (int r = 0; r < 4; ++r) {
            float v[8];
#pragma unroll
            for (int ns = 0; ns < 8; ++ns) {
                float x = s[ns][r];
                x = (x > 0.f) ? x : 0.2f * x;
                v[ns] = x + mk[ns];
            }
            float m0 = fmaxf(fmaxf(fmaxf(v[0], v[1]), fmaxf(v[2], v[3])),
                             fmaxf(fmaxf(v[4], v[5]), fmaxf(v[6], v[7])));
#pragma unroll
            for (int off = 1; off < 16; off <<= 1)
                m0 = fmaxf(m0, __shfl_xor(m0, off, 64));
            float mnew = fmaxf(mrun[r], m0);
            float sc = __expf(mrun[r] - mnew);
            mrun[r] = mnew;
            float rs = 0.f;
            float p[8];
#pragma unroll
            for (int ns = 0; ns < 8; ++ns) { p[ns] = __expf(v[ns] - mnew); rs += p[ns]; }
#pragma unroll
            for (int off = 1; off < 16; off <<= 1)
                rs += __shfl_xor(rs, off, 64);
            lrun[r] = lrun[r] * sc + rs;
            scs[r] = sc;
            int prow = lg * 4 + r;
#pragma unroll
            for (int ns = 0; ns < 8; ++ns) {
                int pb = (prow * 256 + (ns * 16 + l15) * 2) ^ ((prow & 7) << 4);
                *(_Float16*)(smem + P_S + wave * 4096 + pb) = (_Float16)p[ns];
            }
        }
#pragma unroll
        for (int ns = 0; ns < 4; ++ns)
#pragma unroll
            for (int r = 0; r < 4; ++r) o[ns][r] *= scs[r];

        __syncthreads();   // [1] P visible

        // -- O += P @ V --
        __builtin_amdgcn_s_setprio(1);
#pragma unroll
        for (int kc = 0; kc < 4; ++kc) {
            int pb = (l15 * 256 + kc * 64 + lg * 16) ^ ((l15 & 7) << 4);
            f16x8 pf = *(const f16x8*)(smem + P_S + wave * 4096 + pb);
#pragma unroll
            for (int ns = 0; ns < 4; ++ns) {
                int vrow = ns * 16 + l15;
                int vb = (vrow * 256 + kc * 64 + lg * 16) ^
                         ((((vrow & 7) ^ ((vrow >> 3) & 7)) << 4));
                f16x8 vf = *(const f16x8*)(smem + VT_S + vb);
                o[ns] = __builtin_amdgcn_mfma_f32_16x16x32_f16(pf, vf, o[ns], 0, 0, 0);
            }
        }
        __builtin_amdgcn_s_setprio(0);

        __syncthreads();   // [2] all reads of tile kt drained

        if (kt + 1 < NTT) stage_write();

        __syncthreads();   // [3] staging visible
    }

    // ---- epilogue ----
#pragma unroll
    for (int r = 0; r < 4; ++r) {
        float inv = 1.f / lrun[r];
        int row = q0 + wave * 16 + lg * 4 + r;
#pragma unroll
        for (int ns = 0; ns < 4; ++ns)
            out[base + (size_t)row * D_ + ns * 16 + l15] =
                fmaxf(o[ns][r] * inv, 0.f);
    }
}

extern "C" void kernel_launch(void* const* d_in, const int* in_sizes, int n_in,
                              void* d_out, int out_size, void* d_ws, size_t ws_size,
                              hipStream_t stream) {
    const float* Hin  = (const float*)d_in[0];
    const float* Hk   = (const float*)d_in[1];
    const float* Hv   = (const float*)d_in[2];
    const float* A    = (const float*)d_in[3];
    const float* mask = (const float*)d_in[4];
    const float* W    = (const float*)d_in[5];
    const float* bb   = (const float*)d_in[6];
    const float* av   = (const float*)d_in[7];
    const float* ba   = (const float*)d_in[8];
    const float* pw   = (const float*)d_in[9];
    float* out = (float*)d_out;
    float* ws  = (float*)d_ws;      // avAp: 256 KB (proven available)
    float* ApS = out;               // Ap scratch in d_out (fully overwritten by flash)

    prep_Ap<<<dim3(B_ * H_, 4), 256, 0, stream>>>(A, W, bb, pw, ApS);
    prep_avAp2<<<dim3(B_ * H_, 4), 256, 0, stream>>>(ApS, av, ba, ws);
    flash5<<<dim3(S_ / TS, B_ * H_), 256, 0, stream>>>(Hin, Hk, Hv, mask, ws, out);
}

// Round 12
// 183.603 us; speedup vs baseline: 1.2446x; 1.2446x over previous
//
#include <hip/hip_runtime.h>
#include <cmath>

#define B_ 2
#define H_ 8
#define S_ 2048
#define D_ 64
#define TS 64
#define NT (S_ / TS)
#define LDST 68

typedef __attribute__((ext_vector_type(8))) _Float16 f16x8;
typedef __attribute__((ext_vector_type(4))) float f32x4;

// ---------------------------------------------------------------------------
// Kernel 1: avAp = a_vec @ ((relu(W@A+b)+eps)^pw) + ba   (proven R9 version)
// ---------------------------------------------------------------------------
__global__ __launch_bounds__(256) void prep_avAp(
    const float* __restrict__ A, const float* __restrict__ W,
    const float* __restrict__ bb, const float* __restrict__ av,
    const float* __restrict__ ba, const float* __restrict__ pw,
    float* __restrict__ avAp)
{
    __shared__ float s0[TS * LDST];
    __shared__ float s1[TS * LDST];
    const int tid = threadIdx.x;
    const int ty = tid >> 4, tx = tid & 15;
    const int bh = blockIdx.x;
    const int h = bh & (H_ - 1);

    const float4* W4 = (const float4*)(W + h * D_ * D_);
    const float4* A4 = (const float4*)(A + bh * D_ * D_);
#pragma unroll
    for (int it = 0; it < 4; ++it) {
        int idx = tid + it * 256;
        int r = idx >> 4, c = idx & 15;
        *(float4*)&s0[r * LDST + c * 4] = W4[idx];
        *(float4*)&s1[r * LDST + c * 4] = A4[idx];
    }
    __syncthreads();

    float acc[4][4] = {};
    for (int d = 0; d < D_; ++d) {
        float4 a4 = *(const float4*)&s1[d * LDST + tx * 4];
#pragma unroll
        for (int i = 0; i < 4; ++i) {
            float w = s0[(ty * 4 + i) * LDST + d];
            acc[i][0] += w * a4.x; acc[i][1] += w * a4.y;
            acc[i][2] += w * a4.z; acc[i][3] += w * a4.w;
        }
    }
    __syncthreads();

#pragma unroll
    for (int i = 0; i < 4; ++i) {
        int f = ty * 4 + i;
        float4 b4 = *(const float4*)&bb[(h * D_ + f) * D_ + tx * 4];
        float4 p4 = *(const float4*)&pw[(h * D_ + f) * D_ + tx * 4];
        float vb[4] = {b4.x, b4.y, b4.z, b4.w};
        float vp[4] = {p4.x, p4.y, p4.z, p4.w};
#pragma unroll
        for (int j = 0; j < 4; ++j) {
            float aw = fmaxf(acc[i][j] + vb[j], 0.f) + 1e-9f;
            s0[f * LDST + tx * 4 + j] = exp2f(vp[j] * __log2f(aw));
        }
    }
    const float4* av4 = (const float4*)(av + h * D_ * D_);
#pragma unroll
    for (int it = 0; it < 4; ++it) {
        int idx = tid + it * 256;
        int r = idx >> 4, c = idx & 15;
        *(float4*)&s1[r * LDST + c * 4] = av4[idx];
    }
    __syncthreads();

    float acc2[4][4] = {};
    for (int d = 0; d < D_; ++d) {
        float4 a4 = *(const float4*)&s0[d * LDST + tx * 4];
#pragma unroll
        for (int i = 0; i < 4; ++i) {
            float w = s1[(ty * 4 + i) * LDST + d];
            acc2[i][0] += w * a4.x; acc2[i][1] += w * a4.y;
            acc2[i][2] += w * a4.z; acc2[i][3] += w * a4.w;
        }
    }
#pragma unroll
    for (int i = 0; i < 4; ++i) {
        int f = ty * 4 + i;
        float4 ba4 = *(const float4*)&ba[(h * D_ + f) * D_ + tx * 4];
        float4 o = make_float4(acc2[i][0] + ba4.x, acc2[i][1] + ba4.y,
                               acc2[i][2] + ba4.z, acc2[i][3] + ba4.w);
        *(float4*)&avAp[bh * D_ * D_ + f * D_ + tx * 4] = o;
    }
}

// ---------------------------------------------------------------------------
// Kernel 2 "flash6": flash4's proven 3-barrier single-buffer skeleton (KV=64,
// 4 waves, reg-prefetch), LDS cut to 52224 B -> 3 blocks/CU:
//   - MROW deleted; mask loaded per-tile from global (L2-hot, hidden under QK)
//   - loop map: KH@0(8K) KL@8192(8K) VT@16384(8K) P@24576(4x2K)  [32K total]
//   - prologue overlay: AVP@0 HIN@17408 QP@34816 (f32 [64][68] each)
// Barriers/tile unchanged: [1] P visible  [2] reads drained  [3] staging visible
// ---------------------------------------------------------------------------
#define KH_S 0
#define KL_S 8192
#define VT_S 16384
#define P_S  24576
#define QP_S 34816
#define AVP_S 0
#define HIN_S 17408
#define SMEM_SZ 52224

__global__ __launch_bounds__(256) void flash6(
    const float* __restrict__ Hin, const float* __restrict__ Hk,
    const float* __restrict__ Hv, const float* __restrict__ maskg,
    const float* __restrict__ avAp, float* __restrict__ out)
{
    __shared__ __align__(16) char smem[SMEM_SZ];
    float* AVP = (float*)(smem + AVP_S);
    float* HIN = (float*)(smem + HIN_S);
    float* QP  = (float*)(smem + QP_S);

    const int tid = threadIdx.x;
    const int wave = tid >> 6, lane = tid & 63;
    const int l15 = lane & 15, lg = lane >> 4;
    const int qt = blockIdx.x, bh = blockIdx.y;
    const int b = bh >> 3;
    const size_t base = (size_t)bh * S_ * D_;
    const int q0 = qt * TS;
    const float* mrow = maskg + b * S_;

    // ---- Phase A: Qp = Hin_tile @ avAp (f32 in LDS) ----
    {
        const float4* a4 = (const float4*)(avAp + bh * D_ * D_);
        const float4* h4 = (const float4*)(Hin + base + (size_t)q0 * D_);
#pragma unroll
        for (int i = 0; i < 4; ++i) {
            int f = tid + i * 256;
            int r = f >> 4, c = (f & 15) * 4;
            *(float4*)&AVP[r * LDST + c] = a4[f];
            *(float4*)&HIN[r * LDST + c] = h4[f];
        }
    }
    __syncthreads();
    {
        const int tx = tid & 15, ty = tid >> 4;
        float acc[4][4] = {};
        for (int d = 0; d < D_; ++d) {
            float4 av = *(const float4*)&AVP[d * LDST + tx * 4];
#pragma unroll
            for (int rr = 0; rr < 4; ++rr) {
                float h = HIN[(ty * 4 + rr) * LDST + d];
                acc[rr][0] += h * av.x; acc[rr][1] += h * av.y;
                acc[rr][2] += h * av.z; acc[rr][3] += h * av.w;
            }
        }
#pragma unroll
        for (int rr = 0; rr < 4; ++rr)
            *(float4*)&QP[(ty * 4 + rr) * LDST + tx * 4] =
                make_float4(acc[rr][0], acc[rr][1], acc[rr][2], acc[rr][3]);
    }
    __syncthreads();   // AVP/HIN reads done; QP visible

    // ---- extract Q A-frags (x0.125 folded), hi/lo f16 (QP never rewritten) ----
    f16x8 qAh[2], qAl[2];
#pragma unroll
    for (int kc = 0; kc < 2; ++kc) {
        int row = wave * 16 + l15;
        int k0 = kc * 32 + lg * 8;
        float4 v0 = *(const float4*)&QP[row * LDST + k0];
        float4 v1 = *(const float4*)&QP[row * LDST + k0 + 4];
        float xs[8] = {v0.x, v0.y, v0.z, v0.w, v1.x, v1.y, v1.z, v1.w};
#pragma unroll
        for (int j = 0; j < 8; ++j) {
            float x = xs[j] * 0.125f;
            _Float16 hh = (_Float16)x;
            qAh[kc][j] = hh;
            qAl[kc][j] = (_Float16)(x - (float)hh);
        }
    }

    // ---- stage helpers (single buffer, KV=64) ----
    float4 kreg[2][2], vreg[2][2];
    auto stage_load = [&](int kt) {
        const float* Kg = Hk + base + (size_t)kt * TS * D_;
        const float* Vg = Hv + base + (size_t)kt * TS * D_;
#pragma unroll
        for (int i = 0; i < 2; ++i) {
            int c = tid + i * 256;
            kreg[i][0] = *(const float4*)(Kg + c * 8);
            kreg[i][1] = *(const float4*)(Kg + c * 8 + 4);
            vreg[i][0] = *(const float4*)(Vg + c * 8);
            vreg[i][1] = *(const float4*)(Vg + c * 8 + 4);
        }
    };
    auto stage_write = [&]() {
#pragma unroll
        for (int i = 0; i < 2; ++i) {
            int c = tid + i * 256;
            int r = c >> 3, c8 = c & 7;
            float xs[8] = {kreg[i][0].x, kreg[i][0].y, kreg[i][0].z, kreg[i][0].w,
                           kreg[i][1].x, kreg[i][1].y, kreg[i][1].z, kreg[i][1].w};
            f16x8 h, l;
#pragma unroll
            for (int e = 0; e < 8; ++e) {
                _Float16 hh = (_Float16)xs[e];
                h[e] = hh; l[e] = (_Float16)(xs[e] - (float)hh);
            }
            int byte = (r * 128 + c8 * 16) ^ ((r & 7) << 4);
            *(f16x8*)(smem + KH_S + byte) = h;
            *(f16x8*)(smem + KL_S + byte) = l;
            float vs[8] = {vreg[i][0].x, vreg[i][0].y, vreg[i][0].z, vreg[i][0].w,
                           vreg[i][1].x, vreg[i][1].y, vreg[i][1].z, vreg[i][1].w};
#pragma unroll
            for (int e = 0; e < 8; ++e) {
                int vr = c8 * 8 + e;
                int vb = (vr * 128 + r * 2) ^
                         ((((vr & 7) ^ ((vr >> 3) & 7)) << 4));
                *(_Float16*)(smem + VT_S + vb) = (_Float16)vs[e];
            }
        }
    };

    // ---- prologue: tile 0 staged ----
    stage_load(0);
    stage_write();
    __syncthreads();

    float mrun[4], lrun[4];
    f32x4 o[4];
#pragma unroll
    for (int i = 0; i < 4; ++i) {
        mrun[i] = -INFINITY; lrun[i] = 0.f;
        o[i] = (f32x4){0.f, 0.f, 0.f, 0.f};
    }

    for (int kt = 0; kt < NT; ++kt) {
        if (kt + 1 < NT) stage_load(kt + 1);   // prefetch next tile into regs

        // mask values for this tile (L2-hot global; latency hides under QK)
        float mk[4];
#pragma unroll
        for (int ns = 0; ns < 4; ++ns)
            mk[ns] = -1e9f * mrow[kt * TS + ns * 16 + l15];

        // -- QK^T, 3-term hi/lo --
        f32x4 s[4];
#pragma unroll
        for (int ns = 0; ns < 4; ++ns) s[ns] = (f32x4){0.f, 0.f, 0.f, 0.f};
        __builtin_amdgcn_s_setprio(1);
#pragma unroll
        for (int ns = 0; ns < 4; ++ns)
#pragma unroll
            for (int kc = 0; kc < 2; ++kc) {
                int row = ns * 16 + l15;
                int byte = (row * 128 + kc * 64 + lg * 16) ^ ((row & 7) << 4);
                f16x8 kh = *(const f16x8*)(smem + KH_S + byte);
                f16x8 kl = *(const f16x8*)(smem + KL_S + byte);
                s[ns] = __builtin_amdgcn_mfma_f32_16x16x32_f16(qAh[kc], kh, s[ns], 0, 0, 0);
                s[ns] = __builtin_amdgcn_mfma_f32_16x16x32_f16(qAl[kc], kh, s[ns], 0, 0, 0);
                s[ns] = __builtin_amdgcn_mfma_f32_16x16x32_f16(qAh[kc], kl, s[ns], 0, 0, 0);
            }
        __builtin_amdgcn_s_setprio(0);

        // -- leaky + mask + online softmax (row = lg*4+r, col = ns*16+l15) --
        float scs[4];
#pragma unroll
        for (int r = 0; r < 4; ++r) {
            float v[4];
#pragma unroll
            for (int ns = 0; ns < 4; ++ns) {
                float x = s[ns][r];
                x = (x > 0.f) ? x : 0.2f * x;
                v[ns] = x + mk[ns];
            }
            float m0 = fmaxf(fmaxf(v[0], v[1]), fmaxf(v[2], v[3]));
#pragma unroll
            for (int off = 1; off < 16; off <<= 1)
                m0 = fmaxf(m0, __shfl_xor(m0, off, 64));
            float mnew = fmaxf(mrun[r], m0);
            float sc = __expf(mrun[r] - mnew);
            mrun[r] = mnew;
            float rs = 0.f;
            float p[4];
#pragma unroll
            for (int ns = 0; ns < 4; ++ns) { p[ns] = __expf(v[ns] - mnew); rs += p[ns]; }
#pragma unroll
            for (int off = 1; off < 16; off <<= 1)
                rs += __shfl_xor(rs, off, 64);
            lrun[r] = lrun[r] * sc + rs;
            scs[r] = sc;
            int prow = lg * 4 + r;
#pragma unroll
            for (int ns = 0; ns < 4; ++ns) {
                int pb = (prow * 128 + (ns * 16 + l15) * 2) ^ ((prow & 7) << 4);
                *(_Float16*)(smem + P_S + wave * 2048 + pb) = (_Float16)p[ns];
            }
        }
#pragma unroll
        for (int ns = 0; ns < 4; ++ns)
#pragma unroll
            for (int r = 0; r < 4; ++r) o[ns][r] *= scs[r];

        __syncthreads();   // [1] P visible

        // -- O += P @ V --
        __builtin_amdgcn_s_setprio(1);
#pragma unroll
        for (int kc = 0; kc < 2; ++kc) {
            int pb = (l15 * 128 + kc * 64 + lg * 16) ^ ((l15 & 7) << 4);
            f16x8 pf = *(const f16x8*)(smem + P_S + wave * 2048 + pb);
#pragma unroll
            for (int ns = 0; ns < 4; ++ns) {
                int vrow = ns * 16 + l15;
                int vb = (vrow * 128 + kc * 64 + lg * 16) ^
                         ((((vrow & 7) ^ ((vrow >> 3) & 7)) << 4));
                f16x8 vf = *(const f16x8*)(smem + VT_S + vb);
                o[ns] = __builtin_amdgcn_mfma_f32_16x16x32_f16(pf, vf, o[ns], 0, 0, 0);
            }
        }
        __builtin_amdgcn_s_setprio(0);

        __syncthreads();   // [2] all reads of tile kt drained

        if (kt + 1 < NT) stage_write();  // overwrite buffer with tile kt+1

        __syncthreads();   // [3] staging visible
    }

    // ---- epilogue ----
#pragma unroll
    for (int r = 0; r < 4; ++r) {
        float inv = 1.f / lrun[r];
        int row = q0 + wave * 16 + lg * 4 + r;
#pragma unroll
        for (int ns = 0; ns < 4; ++ns)
            out[base + (size_t)row * D_ + ns * 16 + l15] =
                fmaxf(o[ns][r] * inv, 0.f);
    }
}

extern "C" void kernel_launch(void* const* d_in, const int* in_sizes, int n_in,
                              void* d_out, int out_size, void* d_ws, size_t ws_size,
                              hipStream_t stream) {
    const float* Hin  = (const float*)d_in[0];
    const float* Hk   = (const float*)d_in[1];
    const float* Hv   = (const float*)d_in[2];
    const float* A    = (const float*)d_in[3];
    const float* mask = (const float*)d_in[4];
    const float* W    = (const float*)d_in[5];
    const float* bb   = (const float*)d_in[6];
    const float* av   = (const float*)d_in[7];
    const float* ba   = (const float*)d_in[8];
    const float* pw   = (const float*)d_in[9];
    float* out = (float*)d_out;
    float* ws  = (float*)d_ws;

    prep_avAp<<<B_ * H_, 256, 0, stream>>>(A, W, bb, av, ba, pw, ws);
    flash6<<<dim3(NT, B_ * H_), 256, 0, stream>>>(Hin, Hk, Hv, mask, ws, out);
}

// Round 13
// 169.040 us; speedup vs baseline: 1.3518x; 1.0861x over previous
//
#include <hip/hip_runtime.h>
#include <hip/hip_fp16.h>
#include <cmath>

#define B_ 2
#define H_ 8
#define S_ 2048
#define D_ 64
#define TS 64
#define NT (S_ / TS)
#define LDST 68

typedef __attribute__((ext_vector_type(8))) _Float16 f16x8;
typedef __attribute__((ext_vector_type(4))) float f32x4;

// ---------------------------------------------------------------------------
// Kernel 1: avAp = a_vec @ ((relu(W@A+b)+eps)^pw) + ba   (proven R9 version)
// ---------------------------------------------------------------------------
__global__ __launch_bounds__(256) void prep_avAp(
    const float* __restrict__ A, const float* __restrict__ W,
    const float* __restrict__ bb, const float* __restrict__ av,
    const float* __restrict__ ba, const float* __restrict__ pw,
    float* __restrict__ avAp)
{
    __shared__ float s0[TS * LDST];
    __shared__ float s1[TS * LDST];
    const int tid = threadIdx.x;
    const int ty = tid >> 4, tx = tid & 15;
    const int bh = blockIdx.x;
    const int h = bh & (H_ - 1);

    const float4* W4 = (const float4*)(W + h * D_ * D_);
    const float4* A4 = (const float4*)(A + bh * D_ * D_);
#pragma unroll
    for (int it = 0; it < 4; ++it) {
        int idx = tid + it * 256;
        int r = idx >> 4, c = idx & 15;
        *(float4*)&s0[r * LDST + c * 4] = W4[idx];
        *(float4*)&s1[r * LDST + c * 4] = A4[idx];
    }
    __syncthreads();

    float acc[4][4] = {};
    for (int d = 0; d < D_; ++d) {
        float4 a4 = *(const float4*)&s1[d * LDST + tx * 4];
#pragma unroll
        for (int i = 0; i < 4; ++i) {
            float w = s0[(ty * 4 + i) * LDST + d];
            acc[i][0] += w * a4.x; acc[i][1] += w * a4.y;
            acc[i][2] += w * a4.z; acc[i][3] += w * a4.w;
        }
    }
    __syncthreads();

#pragma unroll
    for (int i = 0; i < 4; ++i) {
        int f = ty * 4 + i;
        float4 b4 = *(const float4*)&bb[(h * D_ + f) * D_ + tx * 4];
        float4 p4 = *(const float4*)&pw[(h * D_ + f) * D_ + tx * 4];
        float vb[4] = {b4.x, b4.y, b4.z, b4.w};
        float vp[4] = {p4.x, p4.y, p4.z, p4.w};
#pragma unroll
        for (int j = 0; j < 4; ++j) {
            float aw = fmaxf(acc[i][j] + vb[j], 0.f) + 1e-9f;
            s0[f * LDST + tx * 4 + j] = exp2f(vp[j] * __log2f(aw));
        }
    }
    const float4* av4 = (const float4*)(av + h * D_ * D_);
#pragma unroll
    for (int it = 0; it < 4; ++it) {
        int idx = tid + it * 256;
        int r = idx >> 4, c = idx & 15;
        *(float4*)&s1[r * LDST + c * 4] = av4[idx];
    }
    __syncthreads();

    float acc2[4][4] = {};
    for (int d = 0; d < D_; ++d) {
        float4 a4 = *(const float4*)&s0[d * LDST + tx * 4];
#pragma unroll
        for (int i = 0; i < 4; ++i) {
            float w = s1[(ty * 4 + i) * LDST + d];
            acc2[i][0] += w * a4.x; acc2[i][1] += w * a4.y;
            acc2[i][2] += w * a4.z; acc2[i][3] += w * a4.w;
        }
    }
#pragma unroll
    for (int i = 0; i < 4; ++i) {
        int f = ty * 4 + i;
        float4 ba4 = *(const float4*)&ba[(h * D_ + f) * D_ + tx * 4];
        float4 o = make_float4(acc2[i][0] + ba4.x, acc2[i][1] + ba4.y,
                               acc2[i][2] + ba4.z, acc2[i][3] + ba4.w);
        *(float4*)&avAp[bh * D_ * D_ + f * D_ + tx * 4] = o;
    }
}

// ---------------------------------------------------------------------------
// Kernel 2 "flash7": swapped-operand QK^T (s = mfma(K, Q)) -> P lives in
// registers; softmax per-lane scalar; PV = mfma(V^T, P^T) with a 16-shfl
// lane-group exchange building the P^T B-fragments. NO P in LDS -> barrier
// [1] deleted. Single K/V buffer, 2 barriers/tile with flash4's proven
// write-after-read edges.
// LDS: KH@0(8K) KL@8192(8K) VT@16384(8K); prologue overlay AVP@0 HIN@17408
// QP@34816 (f32[64][68]); SMEM 52224 B.
// ---------------------------------------------------------------------------
#define KH_S 0
#define KL_S 8192
#define VT_S 16384
#define QP_S 34816
#define AVP_S 0
#define HIN_S 17408
#define SMEM_SZ 52224

__global__ __launch_bounds__(256) void flash7(
    const float* __restrict__ Hin, const float* __restrict__ Hk,
    const float* __restrict__ Hv, const float* __restrict__ maskg,
    const float* __restrict__ avAp, float* __restrict__ out)
{
    __shared__ __align__(16) char smem[SMEM_SZ];
    float* AVP = (float*)(smem + AVP_S);
    float* HIN = (float*)(smem + HIN_S);
    float* QP  = (float*)(smem + QP_S);

    const int tid = threadIdx.x;
    const int wave = tid >> 6, lane = tid & 63;
    const int l15 = lane & 15, lg = lane >> 4;
    const int qt = blockIdx.x, bh = blockIdx.y;
    const int b = bh >> 3;
    const size_t base = (size_t)bh * S_ * D_;
    const int q0 = qt * TS;
    const float* mrow = maskg + b * S_;

    // ---- Phase A: Qp = Hin_tile @ avAp (f32 in LDS) ----
    {
        const float4* a4 = (const float4*)(avAp + bh * D_ * D_);
        const float4* h4 = (const float4*)(Hin + base + (size_t)q0 * D_);
#pragma unroll
        for (int i = 0; i < 4; ++i) {
            int f = tid + i * 256;
            int r = f >> 4, c = (f & 15) * 4;
            *(float4*)&AVP[r * LDST + c] = a4[f];
            *(float4*)&HIN[r * LDST + c] = h4[f];
        }
    }
    __syncthreads();
    {
        const int tx = tid & 15, ty = tid >> 4;
        float acc[4][4] = {};
        for (int d = 0; d < D_; ++d) {
            float4 av = *(const float4*)&AVP[d * LDST + tx * 4];
#pragma unroll
            for (int rr = 0; rr < 4; ++rr) {
                float h = HIN[(ty * 4 + rr) * LDST + d];
                acc[rr][0] += h * av.x; acc[rr][1] += h * av.y;
                acc[rr][2] += h * av.z; acc[rr][3] += h * av.w;
            }
        }
#pragma unroll
        for (int rr = 0; rr < 4; ++rr)
            *(float4*)&QP[(ty * 4 + rr) * LDST + tx * 4] =
                make_float4(acc[rr][0], acc[rr][1], acc[rr][2], acc[rr][3]);
    }
    __syncthreads();   // AVP/HIN reads done; QP visible

    // ---- extract Q B-frags (x0.125 folded), hi/lo f16 (layout unchanged:
    //      col=q=l15, k-elems kc*32+lg*8..+7) ----
    f16x8 qAh[2], qAl[2];
#pragma unroll
    for (int kc = 0; kc < 2; ++kc) {
        int row = wave * 16 + l15;
        int k0 = kc * 32 + lg * 8;
        float4 v0 = *(const float4*)&QP[row * LDST + k0];
        float4 v1 = *(const float4*)&QP[row * LDST + k0 + 4];
        float xs[8] = {v0.x, v0.y, v0.z, v0.w, v1.x, v1.y, v1.z, v1.w};
#pragma unroll
        for (int j = 0; j < 8; ++j) {
            float x = xs[j] * 0.125f;
            _Float16 hh = (_Float16)x;
            qAh[kc][j] = hh;
            qAl[kc][j] = (_Float16)(x - (float)hh);
        }
    }

    // ---- stage helpers (single buffer, KV=64; unchanged from flash6) ----
    float4 kreg[2][2], vreg[2][2];
    auto stage_load = [&](int kt) {
        const float* Kg = Hk + base + (size_t)kt * TS * D_;
        const float* Vg = Hv + base + (size_t)kt * TS * D_;
#pragma unroll
        for (int i = 0; i < 2; ++i) {
            int c = tid + i * 256;
            kreg[i][0] = *(const float4*)(Kg + c * 8);
            kreg[i][1] = *(const float4*)(Kg + c * 8 + 4);
            vreg[i][0] = *(const float4*)(Vg + c * 8);
            vreg[i][1] = *(const float4*)(Vg + c * 8 + 4);
        }
    };
    auto stage_write = [&]() {
#pragma unroll
        for (int i = 0; i < 2; ++i) {
            int c = tid + i * 256;
            int r = c >> 3, c8 = c & 7;
            float xs[8] = {kreg[i][0].x, kreg[i][0].y, kreg[i][0].z, kreg[i][0].w,
                           kreg[i][1].x, kreg[i][1].y, kreg[i][1].z, kreg[i][1].w};
            f16x8 h, l;
#pragma unroll
            for (int e = 0; e < 8; ++e) {
                _Float16 hh = (_Float16)xs[e];
                h[e] = hh; l[e] = (_Float16)(xs[e] - (float)hh);
            }
            int byte = (r * 128 + c8 * 16) ^ ((r & 7) << 4);
            *(f16x8*)(smem + KH_S + byte) = h;
            *(f16x8*)(smem + KL_S + byte) = l;
            float vs[8] = {vreg[i][0].x, vreg[i][0].y, vreg[i][0].z, vreg[i][0].w,
                           vreg[i][1].x, vreg[i][1].y, vreg[i][1].z, vreg[i][1].w};
#pragma unroll
            for (int e = 0; e < 8; ++e) {
                int vr = c8 * 8 + e;
                int vb = (vr * 128 + r * 2) ^
                         ((((vr & 7) ^ ((vr >> 3) & 7)) << 4));
                *(_Float16*)(smem + VT_S + vb) = (_Float16)vs[e];
            }
        }
    };

    // ---- prologue: tile 0 staged ----
    stage_load(0);
    stage_write();
    __syncthreads();

    float mrun = -INFINITY, lrun = 0.f;   // per-lane scalars (q = l15)
    f32x4 o[4];
#pragma unroll
    for (int i = 0; i < 4; ++i) o[i] = (f32x4){0.f, 0.f, 0.f, 0.f};

    const int srcA = l15 + (lg & 1) * 32;   // lane of src k-group (j=0..3)
    const int srcB = srcA + 16;             // lane of src k-group (j=4..7)
    const int ns_sel = lg >> 1;

    for (int kt = 0; kt < NT; ++kt) {
        if (kt + 1 < NT) stage_load(kt + 1);   // prefetch next tile into regs

        // mask float4 per ns: k = kt*64 + ns*16 + lg*4 .. +3
        float4 mk4[4];
#pragma unroll
        for (int ns = 0; ns < 4; ++ns)
            mk4[ns] = *(const float4*)&mrow[kt * TS + ns * 16 + lg * 4];

        // -- QK^T swapped: s[ns][r] = S[k = ns*16+lg*4+r][q = l15] --
        f32x4 s[4];
#pragma unroll
        for (int ns = 0; ns < 4; ++ns) s[ns] = (f32x4){0.f, 0.f, 0.f, 0.f};
        __builtin_amdgcn_s_setprio(1);
#pragma unroll
        for (int ns = 0; ns < 4; ++ns)
#pragma unroll
            for (int kc = 0; kc < 2; ++kc) {
                int row = ns * 16 + l15;
                int byte = (row * 128 + kc * 64 + lg * 16) ^ ((row & 7) << 4);
                f16x8 kh = *(const f16x8*)(smem + KH_S + byte);
                f16x8 kl = *(const f16x8*)(smem + KL_S + byte);
                s[ns] = __builtin_amdgcn_mfma_f32_16x16x32_f16(kh, qAh[kc], s[ns], 0, 0, 0);
                s[ns] = __builtin_amdgcn_mfma_f32_16x16x32_f16(kl, qAh[kc], s[ns], 0, 0, 0);
                s[ns] = __builtin_amdgcn_mfma_f32_16x16x32_f16(kh, qAl[kc], s[ns], 0, 0, 0);
            }
        __builtin_amdgcn_s_setprio(0);

        // -- leaky + mask + online softmax, fully per-lane --
        float xmax = -INFINITY;
#pragma unroll
        for (int ns = 0; ns < 4; ++ns) {
            float m[4] = {mk4[ns].x, mk4[ns].y, mk4[ns].z, mk4[ns].w};
#pragma unroll
            for (int r = 0; r < 4; ++r) {
                float x = s[ns][r];
                x = fmaxf(x, 0.2f * x);            // leaky_relu
                x = fmaf(m[r], -1e9f, x);          // + mask*(-1e9)
                s[ns][r] = x;
                xmax = fmaxf(xmax, x);
            }
        }
        xmax = fmaxf(xmax, __shfl_xor(xmax, 16, 64));
        xmax = fmaxf(xmax, __shfl_xor(xmax, 32, 64));
        float mnew = fmaxf(mrun, xmax);
        float sc = __expf(mrun - mnew);
        mrun = mnew;
        float rs = 0.f;
#pragma unroll
        for (int ns = 0; ns < 4; ++ns)
#pragma unroll
            for (int r = 0; r < 4; ++r) {
                float p = __expf(s[ns][r] - mnew);
                s[ns][r] = p;
                rs += p;
            }
        rs += __shfl_xor(rs, 16, 64);
        rs += __shfl_xor(rs, 32, 64);
        lrun = lrun * sc + rs;
#pragma unroll
        for (int ns = 0; ns < 4; ++ns)
#pragma unroll
            for (int r = 0; r < 4; ++r) o[ns][r] *= sc;

        // pack P to f16 pairs: pk[ns] = {h2(p0,p1), h2(p2,p3)}
        unsigned pk[4][2];
#pragma unroll
        for (int ns = 0; ns < 4; ++ns) {
            __half2 h01 = __floats2half2_rn(s[ns][0], s[ns][1]);
            __half2 h23 = __floats2half2_rn(s[ns][2], s[ns][3]);
            pk[ns][0] = *(unsigned*)&h01;
            pk[ns][1] = *(unsigned*)&h23;
        }

        // -- PV: O^T = V^T @ P^T ; build P^T B-frags via lane exchange --
        __builtin_amdgcn_s_setprio(1);
#pragma unroll
        for (int kc = 0; kc < 2; ++kc) {
            unsigned a0 = __shfl((int)pk[kc * 2][0], srcA, 64);
            unsigned a1 = __shfl((int)pk[kc * 2][1], srcA, 64);
            unsigned b0 = __shfl((int)pk[kc * 2 + 1][0], srcA, 64);
            unsigned b1 = __shfl((int)pk[kc * 2 + 1][1], srcA, 64);
            unsigned c0 = __shfl((int)pk[kc * 2][0], srcB, 64);
            unsigned c1 = __shfl((int)pk[kc * 2][1], srcB, 64);
            unsigned d0 = __shfl((int)pk[kc * 2 + 1][0], srcB, 64);
            unsigned d1 = __shfl((int)pk[kc * 2 + 1][1], srcB, 64);
            unsigned w[4];
            w[0] = ns_sel ? b0 : a0;
            w[1] = ns_sel ? b1 : a1;
            w[2] = ns_sel ? d0 : c0;
            w[3] = ns_sel ? d1 : c1;
            f16x8 pf = *(f16x8*)w;
#pragma unroll
            for (int ns = 0; ns < 4; ++ns) {
                int vrow = ns * 16 + l15;
                int vb = (vrow * 128 + kc * 64 + lg * 16) ^
                         ((((vrow & 7) ^ ((vrow >> 3) & 7)) << 4));
                f16x8 vf = *(const f16x8*)(smem + VT_S + vb);
                o[ns] = __builtin_amdgcn_mfma_f32_16x16x32_f16(vf, pf, o[ns], 0, 0, 0);
            }
        }
        __builtin_amdgcn_s_setprio(0);

        __syncthreads();   // [A] all KH/KL/VT reads of tile kt drained

        if (kt + 1 < NT) stage_write();  // overwrite buffer with tile kt+1

        __syncthreads();   // [B] staging visible
    }

    // ---- epilogue: O^T[d, q] -> out[q, d]; float4 per ns ----
    {
        float inv = 1.f / lrun;
        int row = q0 + wave * 16 + l15;
#pragma unroll
        for (int ns = 0; ns < 4; ++ns) {
            float4 v = make_float4(fmaxf(o[ns][0] * inv, 0.f),
                                   fmaxf(o[ns][1] * inv, 0.f),
                                   fmaxf(o[ns][2] * inv, 0.f),
                                   fmaxf(o[ns][3] * inv, 0.f));
            *(float4*)&out[base + (size_t)row * D_ + ns * 16 + lg * 4] = v;
        }
    }
}

extern "C" void kernel_launch(void* const* d_in, const int* in_sizes, int n_in,
                              void* d_out, int out_size, void* d_ws, size_t ws_size,
                              hipStream_t stream) {
    const float* Hin  = (const float*)d_in[0];
    const float* Hk   = (const float*)d_in[1];
    const float* Hv   = (const float*)d_in[2];
    const float* A    = (const float*)d_in[3];
    const float* mask = (const float*)d_in[4];
    const float* W    = (const float*)d_in[5];
    const float* bb   = (const float*)d_in[6];
    const float* av   = (const float*)d_in[7];
    const float* ba   = (const float*)d_in[8];
    const float* pw   = (const float*)d_in[9];
    float* out = (float*)d_out;
    float* ws  = (float*)d_ws;

    prep_avAp<<<B_ * H_, 256, 0, stream>>>(A, W, bb, av, ba, pw, ws);
    flash7<<<dim3(NT, B_ * H_), 256, 0, stream>>>(Hin, Hk, Hv, mask, ws, out);
}